// Round 15
// baseline (420.506 us; speedup 1.0000x reference)
//
#include <hip/hip_runtime.h>

typedef unsigned short u16;
typedef unsigned int   u32;
typedef unsigned char  u8;
typedef __attribute__((ext_vector_type(4))) int   i32x4;

constexpr int B_ = 4, S_ = 4096, DIN_ = 2048, DOUT_ = 8192;
constexpr int M_ = B_ * S_;   // 16384
constexpr int N_ = DOUT_;     // 8192
constexpr int K_ = DIN_;      // 2048
constexpr size_t NW_ = (size_t)DOUT_ * DIN_;  // 16,777,216 weights

#define GPTR(p) ((const __attribute__((address_space(1))) void*)(p))
#define LPTR(p) ((__attribute__((address_space(3))) void*)(p))

#define SB0()   __builtin_amdgcn_sched_barrier(0)
#define BAR()   asm volatile("s_barrier" ::: "memory")
#define LGKM0() asm volatile("s_waitcnt lgkmcnt(0)" ::: "memory")
#define VM2()   asm volatile("s_waitcnt vmcnt(2)" ::: "memory")
#define VM0()   asm volatile("s_waitcnt vmcnt(0)" ::: "memory")

// ---------------------------------------------------------------------------
// Pass 1: deterministic fp64 abs-sum partials.
// ---------------------------------------------------------------------------
__global__ __launch_bounds__(256)
void abssum_kernel(const float* __restrict__ w, double* __restrict__ partials)
{
    const int tid = threadIdx.x;
    const float* base = w + (size_t)blockIdx.x * 16384 + tid * 4;
    double s = 0.0;
#pragma unroll
    for (int i = 0; i < 16; ++i) {
        float4 v = *(const float4*)(base + i * 1024);
        s += (double)fabsf(v.x) + (double)fabsf(v.y)
           + (double)fabsf(v.z) + (double)fabsf(v.w);
    }
#pragma unroll
    for (int o = 32; o; o >>= 1) s += __shfl_xor(s, o, 64);
    __shared__ double red[4];
    if ((tid & 63) == 0) red[tid >> 6] = s;
    __syncthreads();
    if (tid == 0) partials[blockIdx.x] = (red[0] + red[1]) + (red[2] + red[3]);
}

__global__ __launch_bounds__(1024)
void finalize_thr(const double* __restrict__ partials, double* __restrict__ thr)
{
    __shared__ double red[1024];
    const int tid = threadIdx.x;
    red[tid] = partials[tid];
    __syncthreads();
    for (int s = 512; s > 0; s >>= 1) {
        if (tid < s) red[tid] += red[tid + s];
        __syncthreads();
    }
    if (tid == 0) *thr = red[0] * (1.0 / (double)NW_);
}

// ---------------------------------------------------------------------------
// Pass 3: ternarize W -> i8 {-1,0,+1}; fp64 compare (threshold razor-thin).
// ---------------------------------------------------------------------------
__global__ __launch_bounds__(256)
void ternarize_kernel(const float* __restrict__ w, const double* __restrict__ thr_p,
                      signed char* __restrict__ wt)
{
    const double thr = *thr_p;
    const size_t i = ((size_t)blockIdx.x * 256 + threadIdx.x) * 4;
    float4 v = *(const float4*)(w + i);
    union { signed char c[4]; u32 u; } p;
    p.c[0] = (signed char)((fabs((double)v.x) > thr) ? (v.x > 0.0f ? 1 : -1) : 0);
    p.c[1] = (signed char)((fabs((double)v.y) > thr) ? (v.y > 0.0f ? 1 : -1) : 0);
    p.c[2] = (signed char)((fabs((double)v.z) > thr) ? (v.z > 0.0f ? 1 : -1) : 0);
    p.c[3] = (signed char)((fabs((double)v.w) > thr) ? (v.w > 0.0f ? 1 : -1) : 0);
    *(u32*)(wt + i) = p.u;
}

// ---------------------------------------------------------------------------
// Pass 4: RMSNorm rows of x (fp32) -> i8 xn with per-row scale (exact i32
// matmul vs ternary weights; only activation quantization contributes error).
// ---------------------------------------------------------------------------
__global__ __launch_bounds__(256)
void rmsnorm_q_kernel(const float* __restrict__ x, const float* __restrict__ gamma,
                      signed char* __restrict__ xn, float* __restrict__ scale)
{
    const int row = blockIdx.x;
    const int tid = threadIdx.x;
    const float* xr = x + (size_t)row * K_;
    float4 a = *(const float4*)(xr + tid * 8);
    float4 b = *(const float4*)(xr + tid * 8 + 4);
    float s = a.x*a.x + a.y*a.y + a.z*a.z + a.w*a.w
            + b.x*b.x + b.y*b.y + b.z*b.z + b.w*b.w;
#pragma unroll
    for (int o = 32; o; o >>= 1) s += __shfl_xor(s, o, 64);
    __shared__ float redsum[4];
    __shared__ float redmax[4];
    if ((tid & 63) == 0) redsum[tid >> 6] = s;
    __syncthreads();
    const float tot = (redsum[0] + redsum[1]) + (redsum[2] + redsum[3]);
    const float r = rsqrtf(tot * (1.0f / (float)K_) + 1.1920928955078125e-07f);
    float4 g0 = *(const float4*)(gamma + tid * 8);
    float4 g1 = *(const float4*)(gamma + tid * 8 + 4);
    float v[8];
    v[0] = a.x * r * g0.x;  v[1] = a.y * r * g0.y;
    v[2] = a.z * r * g0.z;  v[3] = a.w * r * g0.w;
    v[4] = b.x * r * g1.x;  v[5] = b.y * r * g1.y;
    v[6] = b.z * r * g1.z;  v[7] = b.w * r * g1.w;
    float m = 0.0f;
#pragma unroll
    for (int j = 0; j < 8; ++j) m = fmaxf(m, fabsf(v[j]));
#pragma unroll
    for (int o = 32; o; o >>= 1) m = fmaxf(m, __shfl_xor(m, o, 64));
    if ((tid & 63) == 0) redmax[tid >> 6] = m;
    __syncthreads();
    const float rowmax = fmaxf(fmaxf(redmax[0], redmax[1]), fmaxf(redmax[2], redmax[3]));
    const float inv = rowmax > 0.0f ? 127.0f / rowmax : 0.0f;
    union { signed char c[8]; uint2 u; } p;
#pragma unroll
    for (int j = 0; j < 8; ++j) p.c[j] = (signed char)__float2int_rn(v[j] * inv);
    *(uint2*)(xn + (size_t)row * K_ + tid * 8) = p.u;
    if (tid == 0) scale[row] = rowmax * (1.0f / 127.0f);
}

// ---------------------------------------------------------------------------
// Pass 5: GEMM  C[M,N] = scale[m] * (xn_i8[M,K] @ wt_i8[N,K]^T) + bias
// v15: TWO BARRIER DOMAINS PER CU. 256x128 block, BK=64, 8 waves (4Mx2N,
// wave 64x64 out), 48 KiB LDS, launch_bounds(512,4) -> 2 blocks co-resident.
// Block A's post-barrier lgkm-drain overlaps block B's MFMA cluster —
// attacks the ~265K cy/CU sync residual that pinned v2..v14 at 34-43%.
// Register budget: acc 64 + frags 32 + addr ~20 <= 128 -> 16 waves/CU.
//
// LDS: A[2][256][64B] @0 (32KB) | B[2][128][64B] @32768 (16KB). 64B rows,
// swizzle slot = s ^ (row&3) (bank audit: 8 lanes/bank-quad class x 16B
// = 8 cy = b128 minimum, conflict-free). Linear DMA dest, pre-swz source.
//
// Iteration = 2 K-tiles of 64: T0=buf0@k2i, T1=buf1@k2i+1. 4 phases:
//   p0: read a0-3,b01 (buf0) | stage B1@k2i+1 (1 gload) | Q0(T0) 8 MFMA
//   p1: read b23    (buf0) | stage A0@k2i+2 (2)        | Q1(T0)  VM2*
//   p2: read a0-3,b01 (buf1) | stage B0@k2i+2 (1)       | Q0(T1)
//   p3: read b23    (buf1) | stage A1@k2i+3 (2)        | Q1(T1)  VM2*
// Phase body: [reads|stage] BAR lgkm0 setprio1 MFMA setprio0 [VM] BAR.
// Ledger (induction-verified): at p1-VM2 outstanding {A1@2i+1(2), B1@2i+1(1),
// A0@2i+2(2)} -> retires buf1@2i+1's 3, keeps A0. At p3-VM2 outstanding
// {A0(2),B0(1),A1(2)} -> retires buf0@2i+2's 3, keeps A1. Prologue: A0,B0@0,
// A1@64 (5) -> VM2. Tail i=15: p1 VM0 (3 outstanding, no new stages).
// WAR: each region restaged >=1 fenced phase after its last read's lgkm0.
// ---------------------------------------------------------------------------
__global__ __launch_bounds__(512, 4)
void gemm_bt_kernel(const u8* __restrict__ A, const u8* __restrict__ Bt,
                    const float* __restrict__ bias, const float* __restrict__ scale,
                    float* __restrict__ C)
{
    __shared__ alignas(16) u8 sm[49152];
    const char* smc = (const char*)sm;

    const int tid  = threadIdx.x;
    const int lane = tid & 63;
    const int wid  = tid >> 6;         // 0..7
    const int wm   = wid >> 1;         // 0..3
    const int wn   = wid & 1;          // 0..1
    const int hi   = lane >> 4;        // 0..3

    // XCD-aware bijective swizzle: 4096 blocks % 8 == 0 -> 512/XCD
    const int swz = (blockIdx.x & 7) * 512 + (blockIdx.x >> 3);
    const int gm0 = (swz >> 6) * 256;  // 64 M-tiles
    const int gn0 = (swz & 63) * 128;  // 64 N-tiles

    // ---- staging geometry: thread t -> row t>>2, slot t&3; source k-slot
    //      pre-swizzled: (t&3) ^ ((t>>2)&3).
    const int cswel = ((tid & 3) ^ ((tid >> 2) & 3)) * 16;
    const int rbase = tid >> 2;        // 0..127
    const u8* gA = A  + (size_t)(gm0 + rbase) * K_ + cswel;
    const u8* gB = Bt + (size_t)(gn0 + rbase) * K_ + cswel;

    auto STAGE_A = [&](int buf, int kb) {     // 256 rows x 64B = 2 gloads
        u8* d = sm + buf * 16384 + tid * 16;
        const u8* s = gA + kb;
        __builtin_amdgcn_global_load_lds(GPTR(s),                    LPTR(d),        16, 0, 0);
        __builtin_amdgcn_global_load_lds(GPTR(s + (size_t)128 * K_), LPTR(d + 8192), 16, 0, 0);
    };
    auto STAGE_B = [&](int buf, int kb) {     // 128 rows x 64B = 1 gload
        u8* d = sm + 32768 + buf * 8192 + tid * 16;
        __builtin_amdgcn_global_load_lds(GPTR(gB + kb), LPTR(d), 16, 0, 0);
    };

    // ---- read geometry: row R, slot hi; byte = R*64 + ((hi ^ (R&3))<<4);
    //      R&3 == lane&3 for all fragment rows (m*16 === 0 mod 4).
    const int c0 = ((hi ^ (lane & 3)) << 4);
    const int rowbyteA = (wm * 64 + (lane & 15)) * 64;
    const int rowbyteB = (wn * 64 + (lane & 15)) * 64;

#define RA(bufr, m) (*(const i32x4*)(smc + (bufr)*16384 + rowbyteA + (m)*1024 + c0))
#define RB(bufr, n) (*(const i32x4*)(smc + 32768 + (bufr)*8192 + rowbyteB + (n)*1024 + c0))

    i32x4 acc[4][4] = {};
    i32x4 a[4], b01[2], b23[2];

#define MFMA_BLK(BF, NO)                                                           \
    do {                                                                           \
        _Pragma("unroll") for (int m = 0; m < 4; ++m)                              \
        _Pragma("unroll") for (int n = 0; n < 2; ++n)                              \
            acc[m][n + NO] = __builtin_amdgcn_mfma_i32_16x16x64_i8(                \
                a[m], BF[n], acc[m][n + NO], 0, 0, 0);                             \
    } while (0)

#define READ_AB01(bufr)                                                            \
    do {                                                                           \
        _Pragma("unroll") for (int m = 0; m < 4; ++m) a[m] = RA(bufr, m);          \
        _Pragma("unroll") for (int n = 0; n < 2; ++n) b01[n] = RB(bufr, n);        \
    } while (0)
#define READ_B23(bufr)                                                             \
    do { _Pragma("unroll") for (int n = 0; n < 2; ++n) b23[n] = RB(bufr, n + 2); } while (0)

#define PRIO_MFMA(BF, NO)                                                          \
    do { __builtin_amdgcn_s_setprio(1); MFMA_BLK(BF, NO);                          \
         __builtin_amdgcn_s_setprio(0); } while (0)

    // ---- prologue: A0,B0 @k0 (3 gloads), A1 @k64 (2); retire buf0 ----
    STAGE_A(0, 0);
    STAGE_B(0, 0);
    STAGE_A(1, 64);
    VM2(); SB0(); BAR();

    for (int i = 0; i < 16; ++i) {
        const int kb   = i * 128;
        const bool f = (i < 15);

        // ---- p0: reads a,b01(buf0) | stage B1@k(2i+1) | Q0(T0) ----
        READ_AB01(0);
        STAGE_B(1, kb + 64);
        SB0(); BAR(); LGKM0(); SB0();
        PRIO_MFMA(b01, 0);
        SB0(); BAR();

        // ---- p1: reads b23(buf0) | stage A0@k(2i+2) | Q1(T0) | VM ----
        READ_B23(0);
        if (f) STAGE_A(0, kb + 128);
        SB0(); BAR(); LGKM0(); SB0();
        PRIO_MFMA(b23, 2);
        SB0();
        if (f) { VM2(); } else { VM0(); }
        SB0(); BAR();

        // ---- p2: reads a,b01(buf1) | stage B0@k(2i+2) | Q0(T1) ----
        READ_AB01(1);
        if (f) STAGE_B(0, kb + 128);
        SB0(); BAR(); LGKM0(); SB0();
        PRIO_MFMA(b01, 0);
        SB0(); BAR();

        // ---- p3: reads b23(buf1) | stage A1@k(2i+3) | Q1(T1) | VM ----
        READ_B23(1);
        if (f) STAGE_A(1, kb + 192);
        SB0(); BAR(); LGKM0(); SB0();
        PRIO_MFMA(b23, 2);
        SB0();
        if (f) { VM2(); }
        SB0(); BAR();
    }

    // ---- epilogue: C/D col=lane&15, row=hi*4+ri; dequant + bias ----
    const int orow0 = gm0 + wm * 64 + hi * 4;
    const int ocol0 = gn0 + wn * 64 + (lane & 15);
    float bv[4];
#pragma unroll
    for (int n = 0; n < 4; ++n) bv[n] = bias[ocol0 + n * 16];
#pragma unroll
    for (int m = 0; m < 4; ++m) {
#pragma unroll
        for (int ri = 0; ri < 4; ++ri) {
            const int row = orow0 + m * 16 + ri;
            const float sc = scale[row];
#pragma unroll
            for (int n = 0; n < 4; ++n) {
                C[(size_t)row * N_ + (ocol0 + n * 16)] = (float)acc[m][n][ri] * sc + bv[n];
            }
        }
    }
#undef RA
#undef RB
#undef MFMA_BLK
#undef READ_AB01
#undef READ_B23
#undef PRIO_MFMA
}

// ---------------------------------------------------------------------------
// Workspace layout (bytes):
//   [0,8)                    : thr (double)
//   [1024, 9216)             : 1024 fp64 partials
//   [16384, +16MiB)          : wt    i8 [N=8192][K=2048]
//   [+16MiB, +48MiB)         : xn    i8 [M=16384][K=2048]
//   [+48MiB, +48MiB+64KiB)   : scale f32 [M]
// ---------------------------------------------------------------------------
extern "C" void kernel_launch(void* const* d_in, const int* in_sizes, int n_in,
                              void* d_out, int out_size, void* d_ws, size_t ws_size,
                              hipStream_t stream)
{
    const float* x     = (const float*)d_in[0];
    const float* w     = (const float*)d_in[1];
    const float* bias  = (const float*)d_in[2];
    const float* gamma = (const float*)d_in[3];
    float* out = (float*)d_out;

    char* ws = (char*)d_ws;
    double*      thr      = (double*)(ws);
    double*      partials = (double*)(ws + 1024);
    signed char* wt       = (signed char*)(ws + 16384);
    signed char* xn       = (signed char*)(ws + 16384 + NW_);
    float*       scale    = (float*)(ws + 16384 + NW_ + (size_t)M_ * K_);

    abssum_kernel   <<<1024,  256,  0, stream>>>(w, partials);
    finalize_thr    <<<1,     1024, 0, stream>>>(partials, thr);
    ternarize_kernel<<<16384, 256,  0, stream>>>(w, thr, wt);
    rmsnorm_q_kernel<<<M_,    256,  0, stream>>>(x, gamma, xn, scale);
    gemm_bt_kernel  <<<(M_/256)*(N_/128), 512, 0, stream>>>((const u8*)xn, (const u8*)wt, bias, scale, out);
}

// Round 16
// 415.676 us; speedup vs baseline: 1.0116x; 1.0116x over previous
//
#include <hip/hip_runtime.h>

typedef unsigned short u16;
typedef unsigned int   u32;
typedef unsigned char  u8;
typedef __attribute__((ext_vector_type(4))) int   i32x4;

constexpr int B_ = 4, S_ = 4096, DIN_ = 2048, DOUT_ = 8192;
constexpr int M_ = B_ * S_;   // 16384
constexpr int N_ = DOUT_;     // 8192
constexpr int K_ = DIN_;      // 2048
constexpr size_t NW_ = (size_t)DOUT_ * DIN_;  // 16,777,216 weights

#define GPTR(p) ((const __attribute__((address_space(1))) void*)(p))
#define LPTR(p) ((__attribute__((address_space(3))) void*)(p))

#define SB0()   __builtin_amdgcn_sched_barrier(0)
#define BAR()   asm volatile("s_barrier" ::: "memory")
#define LGKM0() asm volatile("s_waitcnt lgkmcnt(0)" ::: "memory")
#define VM2()   asm volatile("s_waitcnt vmcnt(2)" ::: "memory")
#define VM0()   asm volatile("s_waitcnt vmcnt(0)" ::: "memory")

// ---------------------------------------------------------------------------
// Pass 1: deterministic fp64 abs-sum partials.
// ---------------------------------------------------------------------------
__global__ __launch_bounds__(256)
void abssum_kernel(const float* __restrict__ w, double* __restrict__ partials)
{
    const int tid = threadIdx.x;
    const float* base = w + (size_t)blockIdx.x * 16384 + tid * 4;
    double s = 0.0;
#pragma unroll
    for (int i = 0; i < 16; ++i) {
        float4 v = *(const float4*)(base + i * 1024);
        s += (double)fabsf(v.x) + (double)fabsf(v.y)
           + (double)fabsf(v.z) + (double)fabsf(v.w);
    }
#pragma unroll
    for (int o = 32; o; o >>= 1) s += __shfl_xor(s, o, 64);
    __shared__ double red[4];
    if ((tid & 63) == 0) red[tid >> 6] = s;
    __syncthreads();
    if (tid == 0) partials[blockIdx.x] = (red[0] + red[1]) + (red[2] + red[3]);
}

__global__ __launch_bounds__(1024)
void finalize_thr(const double* __restrict__ partials, double* __restrict__ thr)
{
    __shared__ double red[1024];
    const int tid = threadIdx.x;
    red[tid] = partials[tid];
    __syncthreads();
    for (int s = 512; s > 0; s >>= 1) {
        if (tid < s) red[tid] += red[tid + s];
        __syncthreads();
    }
    if (tid == 0) *thr = red[0] * (1.0 / (double)NW_);
}

// ---------------------------------------------------------------------------
// Merged prep: blocks [0,M): RMSNorm row -> i8 + per-row scale;
//              blocks [M, M+16384): ternarize W chunk -> i8 {-1,0,+1}.
// ---------------------------------------------------------------------------
__global__ __launch_bounds__(256)
void prep_kernel(const float* __restrict__ x, const float* __restrict__ gamma,
                 const double* __restrict__ thr_p, const float* __restrict__ w,
                 signed char* __restrict__ wt,
                 signed char* __restrict__ xn, float* __restrict__ scale)
{
    __shared__ float redsum[4];
    __shared__ float redmax[4];
    const int tid = threadIdx.x;

    if (blockIdx.x >= (unsigned)M_) {
        const double thr = *thr_p;
        const size_t i = ((size_t)(blockIdx.x - M_) * 256 + tid) * 4;
        float4 v = *(const float4*)(w + i);
        union { signed char c[4]; u32 u; } p;
        p.c[0] = (signed char)((fabs((double)v.x) > thr) ? (v.x > 0.0f ? 1 : -1) : 0);
        p.c[1] = (signed char)((fabs((double)v.y) > thr) ? (v.y > 0.0f ? 1 : -1) : 0);
        p.c[2] = (signed char)((fabs((double)v.z) > thr) ? (v.z > 0.0f ? 1 : -1) : 0);
        p.c[3] = (signed char)((fabs((double)v.w) > thr) ? (v.w > 0.0f ? 1 : -1) : 0);
        *(u32*)(wt + i) = p.u;
        return;
    }

    const int row = blockIdx.x;
    const float* xr = x + (size_t)row * K_;
    float4 a = *(const float4*)(xr + tid * 8);
    float4 b = *(const float4*)(xr + tid * 8 + 4);
    float s = a.x*a.x + a.y*a.y + a.z*a.z + a.w*a.w
            + b.x*b.x + b.y*b.y + b.z*b.z + b.w*b.w;
#pragma unroll
    for (int o = 32; o; o >>= 1) s += __shfl_xor(s, o, 64);
    if ((tid & 63) == 0) redsum[tid >> 6] = s;
    __syncthreads();
    const float tot = (redsum[0] + redsum[1]) + (redsum[2] + redsum[3]);
    const float r = rsqrtf(tot * (1.0f / (float)K_) + 1.1920928955078125e-07f);
    float4 g0 = *(const float4*)(gamma + tid * 8);
    float4 g1 = *(const float4*)(gamma + tid * 8 + 4);
    float v[8];
    v[0] = a.x * r * g0.x;  v[1] = a.y * r * g0.y;
    v[2] = a.z * r * g0.z;  v[3] = a.w * r * g0.w;
    v[4] = b.x * r * g1.x;  v[5] = b.y * r * g1.y;
    v[6] = b.z * r * g1.z;  v[7] = b.w * r * g1.w;
    float m = 0.0f;
#pragma unroll
    for (int j = 0; j < 8; ++j) m = fmaxf(m, fabsf(v[j]));
#pragma unroll
    for (int o = 32; o; o >>= 1) m = fmaxf(m, __shfl_xor(m, o, 64));
    if ((tid & 63) == 0) redmax[tid >> 6] = m;
    __syncthreads();
    const float rowmax = fmaxf(fmaxf(redmax[0], redmax[1]), fmaxf(redmax[2], redmax[3]));
    const float inv = rowmax > 0.0f ? 127.0f / rowmax : 0.0f;
    union { signed char c[8]; uint2 u; } p;
#pragma unroll
    for (int j = 0; j < 8; ++j) p.c[j] = (signed char)__float2int_rn(v[j] * inv);
    *(uint2*)(xn + (size_t)row * K_ + tid * 8) = p.u;
    if (tid == 0) scale[row] = rowmax * (1.0f / 127.0f);
}

// ---------------------------------------------------------------------------
// Pass 5: GEMM  C[M,N] = scale[m] * (xn_i8[M,K] @ wt_i8[N,K]^T) + bias
// v16 = v15 (two barrier domains/CU: 256x128 block, BK=64, 8 waves 4Mx2N,
// 48 KiB LDS, launch_bounds(512,4) -> 2 blocks/CU) with the 64B-row swizzle
// CORRECTED: f(R) = (R>>1)&3 (was R&3). Bank audit: bank-group(R,slot) =
// (R&1)*16 + slot*4; same-parity rows (8 of 16) now spread over all 4 slots
// (R>>1 cycles 0..3 twice) -> 2 lanes per (parity,slot) class = 2-way = free
// (m136). v15's R&3 gave even rows only slots {0,2} -> 4-way -> measured
// 3.36e7 conflict cycles (4 cy on every ds_read_b128). Both sides change
// together (rule 21): stage source k-slot = (tid&3) ^ ((tid>>3)&3); read
// slot = hi ^ ((lane>>1)&3). Schedule/ledger/barriers byte-identical to v15.
//
// Iteration = 2 K-tiles of 64: T0=buf0@k2i, T1=buf1@k2i+1. 4 phases:
//   p0: read a0-3,b01 (buf0) | stage B1@k2i+1 (1 gload) | Q0(T0) 8 MFMA
//   p1: read b23    (buf0) | stage A0@k2i+2 (2)        | Q1(T0)  VM2*
//   p2: read a0-3,b01 (buf1) | stage B0@k2i+2 (1)       | Q0(T1)
//   p3: read b23    (buf1) | stage A1@k2i+3 (2)        | Q1(T1)  VM2*
// Ledger: p1-VM2 retires buf1@2i+1's 3 loads (keeps A0@2i+2); p3-VM2 retires
// buf0@2i+2's 3 (keeps A1). Prologue 5 -> VM2. Tail i=15: p1 VM0.
// ---------------------------------------------------------------------------
__global__ __launch_bounds__(512, 4)
void gemm_bt_kernel(const u8* __restrict__ A, const u8* __restrict__ Bt,
                    const float* __restrict__ bias, const float* __restrict__ scale,
                    float* __restrict__ C)
{
    __shared__ alignas(16) u8 sm[49152];
    const char* smc = (const char*)sm;

    const int tid  = threadIdx.x;
    const int lane = tid & 63;
    const int wid  = tid >> 6;         // 0..7
    const int wm   = wid >> 1;         // 0..3
    const int wn   = wid & 1;          // 0..1
    const int hi   = lane >> 4;        // 0..3

    // XCD-aware bijective swizzle: 4096 blocks % 8 == 0 -> 512/XCD
    const int swz = (blockIdx.x & 7) * 512 + (blockIdx.x >> 3);
    const int gm0 = (swz >> 6) * 256;  // 64 M-tiles
    const int gn0 = (swz & 63) * 128;  // 64 N-tiles

    // ---- staging geometry: thread t -> row t>>2, slot t&3; source k-slot
    //      pre-swizzled with f(row) = (row>>1)&3 = (t>>3)&3.
    const int cswel = ((tid & 3) ^ ((tid >> 3) & 3)) * 16;
    const int rbase = tid >> 2;        // 0..127
    const u8* gA = A  + (size_t)(gm0 + rbase) * K_ + cswel;
    const u8* gB = Bt + (size_t)(gn0 + rbase) * K_ + cswel;

    auto STAGE_A = [&](int buf, int kb) {     // 256 rows x 64B = 2 gloads
        u8* d = sm + buf * 16384 + tid * 16;
        const u8* s = gA + kb;
        __builtin_amdgcn_global_load_lds(GPTR(s),                    LPTR(d),        16, 0, 0);
        __builtin_amdgcn_global_load_lds(GPTR(s + (size_t)128 * K_), LPTR(d + 8192), 16, 0, 0);
    };
    auto STAGE_B = [&](int buf, int kb) {     // 128 rows x 64B = 1 gload
        u8* d = sm + 32768 + buf * 8192 + tid * 16;
        __builtin_amdgcn_global_load_lds(GPTR(gB + kb), LPTR(d), 16, 0, 0);
    };

    // ---- read geometry: row R = wbase + (lane&15); byte = R*64 +
    //      ((hi ^ ((R>>1)&3))<<4); wbase,m-offsets are multiples of 8 rows
    //      so (R>>1)&3 = ((lane&15)>>1)&3 = (lane>>1)&3 for lane&15.
    const int c0 = ((hi ^ ((lane >> 1) & 3)) << 4);
    const int rowbyteA = (wm * 64 + (lane & 15)) * 64;
    const int rowbyteB = (wn * 64 + (lane & 15)) * 64;

#define RA(bufr, m) (*(const i32x4*)(smc + (bufr)*16384 + rowbyteA + (m)*1024 + c0))
#define RB(bufr, n) (*(const i32x4*)(smc + 32768 + (bufr)*8192 + rowbyteB + (n)*1024 + c0))

    i32x4 acc[4][4] = {};
    i32x4 a[4], b01[2], b23[2];

#define MFMA_BLK(BF, NO)                                                           \
    do {                                                                           \
        _Pragma("unroll") for (int m = 0; m < 4; ++m)                              \
        _Pragma("unroll") for (int n = 0; n < 2; ++n)                              \
            acc[m][n + NO] = __builtin_amdgcn_mfma_i32_16x16x64_i8(                \
                a[m], BF[n], acc[m][n + NO], 0, 0, 0);                             \
    } while (0)

#define READ_AB01(bufr)                                                            \
    do {                                                                           \
        _Pragma("unroll") for (int m = 0; m < 4; ++m) a[m] = RA(bufr, m);          \
        _Pragma("unroll") for (int n = 0; n < 2; ++n) b01[n] = RB(bufr, n);        \
    } while (0)
#define READ_B23(bufr)                                                             \
    do { _Pragma("unroll") for (int n = 0; n < 2; ++n) b23[n] = RB(bufr, n + 2); } while (0)

#define PRIO_MFMA(BF, NO)                                                          \
    do { __builtin_amdgcn_s_setprio(1); MFMA_BLK(BF, NO);                          \
         __builtin_amdgcn_s_setprio(0); } while (0)

    // ---- prologue: A0,B0 @k0 (3 gloads), A1 @k64 (2); retire buf0 ----
    STAGE_A(0, 0);
    STAGE_B(0, 0);
    STAGE_A(1, 64);
    VM2(); SB0(); BAR();

    for (int i = 0; i < 16; ++i) {
        const int kb   = i * 128;
        const bool f = (i < 15);

        // ---- p0: reads a,b01(buf0) | stage B1@k(2i+1) | Q0(T0) ----
        READ_AB01(0);
        STAGE_B(1, kb + 64);
        SB0(); BAR(); LGKM0(); SB0();
        PRIO_MFMA(b01, 0);
        SB0(); BAR();

        // ---- p1: reads b23(buf0) | stage A0@k(2i+2) | Q1(T0) | VM ----
        READ_B23(0);
        if (f) STAGE_A(0, kb + 128);
        SB0(); BAR(); LGKM0(); SB0();
        PRIO_MFMA(b23, 2);
        SB0();
        if (f) { VM2(); } else { VM0(); }
        SB0(); BAR();

        // ---- p2: reads a,b01(buf1) | stage B0@k(2i+2) | Q0(T1) ----
        READ_AB01(1);
        if (f) STAGE_B(0, kb + 128);
        SB0(); BAR(); LGKM0(); SB0();
        PRIO_MFMA(b01, 0);
        SB0(); BAR();

        // ---- p3: reads b23(buf1) | stage A1@k(2i+3) | Q1(T1) | VM ----
        READ_B23(1);
        if (f) STAGE_A(1, kb + 192);
        SB0(); BAR(); LGKM0(); SB0();
        PRIO_MFMA(b23, 2);
        SB0();
        if (f) { VM2(); }
        SB0(); BAR();
    }

    // ---- epilogue: C/D col=lane&15, row=hi*4+ri; dequant + bias ----
    const int orow0 = gm0 + wm * 64 + hi * 4;
    const int ocol0 = gn0 + wn * 64 + (lane & 15);
    float bv[4];
#pragma unroll
    for (int n = 0; n < 4; ++n) bv[n] = bias[ocol0 + n * 16];
#pragma unroll
    for (int m = 0; m < 4; ++m) {
#pragma unroll
        for (int ri = 0; ri < 4; ++ri) {
            const int row = orow0 + m * 16 + ri;
            const float sc = scale[row];
#pragma unroll
            for (int n = 0; n < 4; ++n) {
                C[(size_t)row * N_ + (ocol0 + n * 16)] = (float)acc[m][n][ri] * sc + bv[n];
            }
        }
    }
#undef RA
#undef RB
#undef MFMA_BLK
#undef READ_AB01
#undef READ_B23
#undef PRIO_MFMA
}

// ---------------------------------------------------------------------------
// Workspace layout (bytes):
//   [0,8)                    : thr (double)
//   [1024, 9216)             : 1024 fp64 partials
//   [16384, +16MiB)          : wt    i8 [N=8192][K=2048]
//   [+16MiB, +48MiB)         : xn    i8 [M=16384][K=2048]
//   [+48MiB, +48MiB+64KiB)   : scale f32 [M]
// ---------------------------------------------------------------------------
extern "C" void kernel_launch(void* const* d_in, const int* in_sizes, int n_in,
                              void* d_out, int out_size, void* d_ws, size_t ws_size,
                              hipStream_t stream)
{
    const float* x     = (const float*)d_in[0];
    const float* w     = (const float*)d_in[1];
    const float* bias  = (const float*)d_in[2];
    const float* gamma = (const float*)d_in[3];
    float* out = (float*)d_out;

    char* ws = (char*)d_ws;
    double*      thr      = (double*)(ws);
    double*      partials = (double*)(ws + 1024);
    signed char* wt       = (signed char*)(ws + 16384);
    signed char* xn       = (signed char*)(ws + 16384 + NW_);
    float*       scale    = (float*)(ws + 16384 + NW_ + (size_t)M_ * K_);

    abssum_kernel <<<1024,  256,  0, stream>>>(w, partials);
    finalize_thr  <<<1,     1024, 0, stream>>>(partials, thr);
    prep_kernel   <<<M_ + 16384, 256, 0, stream>>>(x, gamma, thr, w, wt, xn, scale);
    gemm_bt_kernel<<<(M_/256)*(N_/128), 512, 0, stream>>>((const u8*)xn, (const u8*)wt, bias, scale, out);
}